// Round 5
// baseline (305.452 us; speedup 1.0000x reference)
//
#include <hip/hip_runtime.h>

#define NTOK 49
#define NH 6
#define HD 32
#define DIM 192
#define QKV_DIM 576
#define PI_F 3.14159265358979323846f

typedef __bf16 bf16_t;
typedef __bf16 bf16x4 __attribute__((ext_vector_type(4)));
typedef __bf16 bf16x8 __attribute__((ext_vector_type(8)));
typedef float f32x4 __attribute__((ext_vector_type(4)));

// ---------------- Kernel 0: convert weights fp32 -> bf16 ----------------
__global__ __launch_bounds__(256) void cvt_weights(const float* __restrict__ qkv_w,
                                                   const float* __restrict__ proj_w,
                                                   bf16_t* __restrict__ wq,
                                                   bf16_t* __restrict__ wp) {
    int idx = blockIdx.x * 256 + threadIdx.x;
    if (idx < QKV_DIM * DIM) {
        wq[idx] = (bf16_t)qkv_w[idx];
    } else {
        int j = idx - QKV_DIM * DIM;
        if (j < DIM * DIM) wp[j] = (bf16_t)proj_w[j];
    }
}

// ---------------- Kernel 1: fully-fused window attention (R3 dataflow, lean LDS) ----------------
// One block (384 thr = 6 waves) per window; wave w = head w.
// LDS: xo (64x200: x rows 0..48, rows 49..63 zeroed; later O), per-wave scratch
// 2560 elems reused sequentially q(64x40) -> k(64x40) -> vt(32x72) -> P(16x72), bias fp32.
__global__ __launch_bounds__(384) void fused_win_attn(
        const float* __restrict__ x,
        const float* __restrict__ Dp,
        const bf16_t* __restrict__ wq,
        const float* __restrict__ qkv_b,
        const bf16_t* __restrict__ wp,
        const float* __restrict__ proj_b,
        const float* __restrict__ a_p,
        const float* __restrict__ b_p,
        const float* __restrict__ a_r,
        const float* __restrict__ b_r,
        float* __restrict__ out) {
    __shared__ __align__(16) bf16_t xo_sh[64 * 200];       // 25.6 KB: x (padded), later O
    __shared__ __align__(16) bf16_t scr_sh[NH][2560];      // 30.7 KB: q/k/vt/P per wave
    __shared__ float bias_sh[NH][169];                     // 4.1 KB

    const int tid  = threadIdx.x;
    const int w    = tid >> 6;        // wave id == head id
    const int lane = tid & 63;
    const int l16  = lane & 15;
    const int quad = lane >> 4;
    const int win  = blockIdx.x;

    bf16_t* scr    = scr_sh[w];
    float*  bias13 = bias_sh[w];

    // ---- Phase 0: stage x (49x192 fp32 -> bf16 LDS, rows 49..63 zeroed) ----
    const float* xg = x + (size_t)win * (NTOK * DIM);
    for (int u = tid; u < 2352; u += 384) {           // 49*192/4
        int e = u * 4;
        int r = e / 192, c = e - r * 192;
        float4 xv = *(const float4*)(xg + e);
        bf16x4 pk = { (bf16_t)xv.x, (bf16_t)xv.y, (bf16_t)xv.z, (bf16_t)xv.w };
        *(bf16x4*)(&xo_sh[r * 200 + c]) = pk;
    }
    {
        bf16x8 z = {};
        for (int u = tid; u < 360; u += 384) {        // 15*192/8
            int e = u * 8;
            int r = 49 + e / 192, c = e % 192;
            *(bf16x8*)(&xo_sh[r * 200 + c]) = z;
        }
    }

    // ---- bias table for this head (own LDS region, own-wave use only) ----
    const float Dv = Dp[win];
    for (int u = lane; u < 169; u += 64) {
        int dr = u / 13 - 6, da = u % 13 - 6;
        int ri = (dr < 0) ? dr + 13 : dr;
        int ai = (da < 0) ? da + 13 : da;
        float ang_a = (float)da * (2.0f * PI_F / 56.0f);
        float ang_r = Dv * (float)dr * (2.0f * PI_F / 448.0f);
        bias13[u] = a_p[ai * NH + w] * __cosf(ang_a) + b_p[ai * NH + w] * __sinf(ang_a)
                  + a_r[ri * NH + w] * __cosf(ang_r) + b_r[ri * NH + w] * __sinf(ang_r);
    }
    __syncthreads();   // barrier 1: x staged

    // ---- Phase 2: QKV gemm for this head; frags via per-wave scratch ----
    const float scale = 0.17677669529663687f; // 32^-0.5
    bf16x8 qf[4], kf[4], vf[2][2];

    for (int part = 0; part < 3; ++part) {
        const int base_c = part * DIM + w * 32;
        const bf16_t* wg = wq + (size_t)base_c * DIM;
        f32x4 acc[4][2] = {};
#pragma unroll
        for (int ks = 0; ks < 6; ++ks) {
            bf16x8 b0 = *(const bf16x8*)(wg + (size_t)l16 * DIM + ks * 32 + quad * 8);
            bf16x8 b1 = *(const bf16x8*)(wg + (size_t)(16 + l16) * DIM + ks * 32 + quad * 8);
            bf16x8 af[4];
#pragma unroll
            for (int mt = 0; mt < 4; ++mt)
                af[mt] = *(const bf16x8*)(&xo_sh[(mt * 16 + l16) * 200 + ks * 32 + quad * 8]);
#pragma unroll
            for (int mt = 0; mt < 4; ++mt) {
                acc[mt][0] = __builtin_amdgcn_mfma_f32_16x16x32_bf16(af[mt], b0, acc[mt][0], 0, 0, 0);
                acc[mt][1] = __builtin_amdgcn_mfma_f32_16x16x32_bf16(af[mt], b1, acc[mt][1], 0, 0, 0);
            }
        }
        float bb0 = qkv_b[base_c + l16];
        float bb1 = qkv_b[base_c + 16 + l16];
        if (part == 2) {
            // v: transposed into scratch [d][tok], stride 72 (all 64 toks written)
#pragma unroll
            for (int mt = 0; mt < 4; ++mt)
#pragma unroll
                for (int r = 0; r < 4; ++r) {
                    int tok = mt * 16 + quad * 4 + r;
                    scr[l16 * 72 + tok]        = (bf16_t)(acc[mt][0][r] + bb0);
                    scr[(16 + l16) * 72 + tok] = (bf16_t)(acc[mt][1][r] + bb1);
                }
#pragma unroll
            for (int ntd = 0; ntd < 2; ++ntd)
#pragma unroll
                for (int kt = 0; kt < 2; ++kt)
                    vf[ntd][kt] = *(const bf16x8*)(&scr[(ntd * 16 + l16) * 72 + kt * 32 + quad * 8]);
        } else {
            float sc = (part == 0) ? scale : 1.0f;
            // q/k: row-major [tok][d], stride 40 (all 64 toks written)
#pragma unroll
            for (int mt = 0; mt < 4; ++mt)
#pragma unroll
                for (int r = 0; r < 4; ++r) {
                    int tok = mt * 16 + quad * 4 + r;
                    scr[tok * 40 + l16]      = (bf16_t)((acc[mt][0][r] + bb0) * sc);
                    scr[tok * 40 + 16 + l16] = (bf16_t)((acc[mt][1][r] + bb1) * sc);
                }
            if (part == 0) {
#pragma unroll
                for (int nt = 0; nt < 4; ++nt)
                    qf[nt] = *(const bf16x8*)(&scr[(nt * 16 + l16) * 40 + quad * 8]);
            } else {
#pragma unroll
                for (int nt = 0; nt < 4; ++nt)
                    kf[nt] = *(const bf16x8*)(&scr[(nt * 16 + l16) * 40 + quad * 8]);
            }
        }
    }
    __syncthreads();   // barrier 2: all x reads done; xo_sh may become O

    // ---- Phase 3: MFMA attention (R3-exact softmax with max subtraction) ----
    int jh[4], jw[4];
#pragma unroll
    for (int nt = 0; nt < 4; ++nt) {
        int j = nt * 16 + l16;
        jh[nt] = j / 7;
        jw[nt] = j - 7 * jh[nt];
    }
    bf16_t* P = scr;   // 16 x 72

    for (int mt = 0; mt < 4; ++mt) {
        f32x4 s[4] = {};
#pragma unroll
        for (int nt = 0; nt < 4; ++nt)
            s[nt] = __builtin_amdgcn_mfma_f32_16x16x32_bf16(qf[mt], kf[nt], s[nt], 0, 0, 0);

        float ev[4][4];
        float rs[4];
#pragma unroll
        for (int r = 0; r < 4; ++r) {
            int i = mt * 16 + quad * 4 + r;
            int ih = i / 7, iw = i - 7 * ih;
            float val[4];
            float mx = -1e30f;
#pragma unroll
            for (int nt = 0; nt < 4; ++nt) {
                int idx = (ih - jh[nt]) * 13 + (iw - jw[nt]) + 84;
                idx = min(max(idx, 0), 168);
                float vv = s[nt][r] + bias13[idx];
                if (nt * 16 + l16 >= 49) vv = -1e30f;
                val[nt] = vv;
                mx = fmaxf(mx, vv);
            }
#pragma unroll
            for (int m = 1; m <= 8; m <<= 1) mx = fmaxf(mx, __shfl_xor(mx, m));
            float sum = 0.f;
#pragma unroll
            for (int nt = 0; nt < 4; ++nt) {
                float e = __expf(val[nt] - mx);
                ev[r][nt] = e;
                sum += e;
            }
#pragma unroll
            for (int m = 1; m <= 8; m <<= 1) sum += __shfl_xor(sum, m);
            rs[r] = 1.0f / sum;
        }

        // P -> per-wave scratch (single-wave RAW; in-order DS)
#pragma unroll
        for (int r = 0; r < 4; ++r)
#pragma unroll
            for (int nt = 0; nt < 4; ++nt)
                P[(quad * 4 + r) * 72 + nt * 16 + l16] = (bf16_t)ev[r][nt];

        bf16x8 pa[2];
#pragma unroll
        for (int kt = 0; kt < 2; ++kt)
            pa[kt] = *(const bf16x8*)(&P[l16 * 72 + kt * 32 + quad * 8]);

        f32x4 o[2] = {};
#pragma unroll
        for (int ntd = 0; ntd < 2; ++ntd)
#pragma unroll
            for (int kt = 0; kt < 2; ++kt)
                o[ntd] = __builtin_amdgcn_mfma_f32_16x16x32_bf16(pa[kt], vf[ntd][kt], o[ntd], 0, 0, 0);

        // O (normalized) -> xo_sh rows [tok][w*32 + d]; rows >=49 stay zero
#pragma unroll
        for (int r = 0; r < 4; ++r) {
            int tok = mt * 16 + quad * 4 + r;
            if (tok < 49) {
                bf16_t* op = &xo_sh[tok * 200 + w * 32];
                op[l16]      = (bf16_t)(o[0][r] * rs[r]);
                op[16 + l16] = (bf16_t)(o[1][r] * rs[r]);
            }
        }
    }
    __syncthreads();   // barrier 3: all heads' O in xo_sh

    // ---- Phase 4: output projection; wave w covers out channels [w*32, w*32+32) ----
    f32x4 pacc[4][2] = {};
#pragma unroll
    for (int ks = 0; ks < 6; ++ks) {
        bf16x8 w0 = *(const bf16x8*)(wp + (size_t)(w * 32 + l16) * DIM + ks * 32 + quad * 8);
        bf16x8 w1 = *(const bf16x8*)(wp + (size_t)(w * 32 + 16 + l16) * DIM + ks * 32 + quad * 8);
        bf16x8 oa[4];
#pragma unroll
        for (int mt = 0; mt < 4; ++mt)
            oa[mt] = *(const bf16x8*)(&xo_sh[(mt * 16 + l16) * 200 + ks * 32 + quad * 8]);
#pragma unroll
        for (int mt = 0; mt < 4; ++mt) {
            pacc[mt][0] = __builtin_amdgcn_mfma_f32_16x16x32_bf16(oa[mt], w0, pacc[mt][0], 0, 0, 0);
            pacc[mt][1] = __builtin_amdgcn_mfma_f32_16x16x32_bf16(oa[mt], w1, pacc[mt][1], 0, 0, 0);
        }
    }

    float pb0 = proj_b[w * 32 + l16];
    float pb1 = proj_b[w * 32 + 16 + l16];
#pragma unroll
    for (int mt = 0; mt < 4; ++mt)
#pragma unroll
        for (int r = 0; r < 4; ++r) {
            int i = mt * 16 + quad * 4 + r;
            if (i < 49) {
                float* op = out + ((size_t)win * NTOK + i) * DIM + w * 32;
                op[l16]      = pacc[mt][0][r] + pb0;
                op[16 + l16] = pacc[mt][1][r] + pb1;
            }
        }
}

extern "C" void kernel_launch(void* const* d_in, const int* in_sizes, int n_in,
                              void* d_out, int out_size, void* d_ws, size_t ws_size,
                              hipStream_t stream) {
    const float* x      = (const float*)d_in[0];
    const float* D      = (const float*)d_in[1];
    const float* qkv_w  = (const float*)d_in[2];
    const float* qkv_b  = (const float*)d_in[3];
    const float* proj_w = (const float*)d_in[4];
    const float* proj_b = (const float*)d_in[5];
    const float* a_p    = (const float*)d_in[6];
    const float* b_p    = (const float*)d_in[7];
    const float* a_r    = (const float*)d_in[8];
    const float* b_r    = (const float*)d_in[9];
    float* out = (float*)d_out;

    const int B_ = in_sizes[0] / (NTOK * DIM);   // 2048 windows

    char* wsp = (char*)d_ws;
    bf16_t* wq = (bf16_t*)wsp; wsp += (size_t)QKV_DIM * DIM * 2;
    bf16_t* wp = (bf16_t*)wsp;

    cvt_weights<<<dim3((QKV_DIM * DIM + DIM * DIM + 255) / 256), dim3(256), 0, stream>>>(
        qkv_w, proj_w, wq, wp);

    fused_win_attn<<<dim3(B_), dim3(384), 0, stream>>>(
        x, D, wq, qkv_b, wp, proj_b, a_p, b_p, a_r, b_r, out);
}